// Round 15
// baseline (200.209 us; speedup 1.0000x reference)
//
#include <hip/hip_runtime.h>

static constexpr int NN  = 100000;   // nodes
static constexpr int NE  = 1200000;  // edges
static constexpr int KIN = 256;      // input dim
static constexpr int HID = 64;       // hidden == output dim

static constexpr int BSH   = 7;                        // log2 nodes-per-bucket
static constexpr int NPB   = 1 << BSH;                 // 128 nodes per bucket
static constexpr int NB    = (NN + NPB - 1) / NPB;     // 782 buckets
static constexpr int CHUNK = 8192;                     // edges per binning block
static constexpr int NBK   = (NE + CHUNK - 1) / CHUNK; // 147 binning blocks

typedef __attribute__((ext_vector_type(8))) __bf16 bf16v8;
typedef __attribute__((ext_vector_type(4))) float f32x4;

// ---------- bf16 helpers (exact widen; RNE narrow)
__device__ __forceinline__ float bf2f(unsigned short u) {
  return __uint_as_float(((unsigned int)u) << 16);
}
__device__ __forceinline__ unsigned short f2bf(float f) {
  unsigned int b = __float_as_uint(f);
  return (unsigned short)((b + 0x7FFFu + ((b >> 16) & 1u)) >> 16);
}

// ---------- both W tables fp32 -> bf16 hi/lo in one launch
__global__ void k_wconv2(const float* __restrict__ W1, __bf16* __restrict__ Whi1, __bf16* __restrict__ Wlo1,
                         const float* __restrict__ W2, __bf16* __restrict__ Whi2, __bf16* __restrict__ Wlo2) {
  int i = blockIdx.x * 256 + threadIdx.x;
  constexpr int n1 = HID * KIN;
  if (i < n1) {
    float v = W1[i];
    __bf16 h = (__bf16)v;
    Whi1[i] = h;
    Wlo1[i] = (__bf16)(v - (float)h);
  } else if (i < n1 + HID * HID) {
    int j = i - n1;
    float v = W2[j];
    __bf16 h = (__bf16)v;
    Whi2[j] = h;
    Wlo2[j] = (__bf16)(v - (float)h);
  }
}

// ---------- pass 1: per-(block,bucket) histogram of dst buckets
__global__ void __launch_bounds__(256) k_bhist(const int* __restrict__ ed, int* __restrict__ bcnt) {
  __shared__ int lcnt[NB];
  int t = threadIdx.x, blk = blockIdx.x;
  for (int i = t; i < NB; i += 256) lcnt[i] = 0;
  __syncthreads();
  int base = blk * CHUNK;
  #pragma unroll
  for (int it = 0; it < CHUNK / 256; ++it) {
    int e = base + it * 256 + t;
    if (e < NE) atomicAdd(&lcnt[ed[NE + e] >> BSH], 1);
  }
  __syncthreads();
  for (int i = t; i < NB; i += 256) bcnt[blk * NB + i] = lcnt[i];
}

// ---------- scan A: per bucket, exclusive prefix over blocks (in place) + totals
__global__ void k_bscan1(int* __restrict__ bcnt, int* __restrict__ tot) {
  int b = blockIdx.x * 256 + threadIdx.x;
  if (b >= NB) return;
  int run = 0;
  for (int k = 0; k < NBK; ++k) {
    int v = bcnt[k * NB + b];
    bcnt[k * NB + b] = run;
    run += v;
  }
  tot[b] = run;
}

// ---------- scan B: exclusive prefix over bucket totals
__global__ void k_bscan2(const int* __restrict__ tot, int* __restrict__ basep) {
  __shared__ int sh[1024];
  int t = threadIdx.x;
  int v = (t < NB) ? tot[t] : 0;
  sh[t] = v;
  __syncthreads();
  #pragma unroll
  for (int off = 1; off < 1024; off <<= 1) {
    int x = (t >= off) ? sh[t - off] : 0;
    __syncthreads();
    sh[t] += x;
    __syncthreads();
  }
  if (t < NB) basep[t] = sh[t] - v;  // exclusive
}

// ---------- pass 2: scatter edges into bucket-grouped array (contiguous per block/bucket)
__global__ void __launch_bounds__(256) k_bin(const int* __restrict__ ed, const int* __restrict__ bcnt,
                                             const int* __restrict__ basep, unsigned* __restrict__ binned) {
  __shared__ int lcnt[NB];
  int t = threadIdx.x, blk = blockIdx.x;
  for (int i = t; i < NB; i += 256) lcnt[i] = 0;
  __syncthreads();
  int base = blk * CHUNK;
  #pragma unroll
  for (int it = 0; it < CHUNK / 256; ++it) {
    int e = base + it * 256 + t;
    if (e < NE) {
      int src = ed[e];
      int dst = ed[NE + e];
      int b = dst >> BSH;
      int r = atomicAdd(&lcnt[b], 1);
      int pos = basep[b] + bcnt[blk * NB + b] + r;
      binned[pos] = (unsigned)src | ((unsigned)(dst & (NPB - 1)) << 17);
    }
  }
}

// ---------- fused per-bucket: degree + dinv + row_ptr (rp = basep[b] + in-bucket prefix).
// No global scans needed: CSR windows coincide with bucket windows.
__global__ void __launch_bounds__(256) k_degb2(const unsigned* __restrict__ binned,
                                               const int* __restrict__ basep, const int* __restrict__ tot,
                                               int* __restrict__ deg, float* __restrict__ dinv,
                                               int* __restrict__ rp) {
  __shared__ int d[NPB];
  __shared__ int sc[NPB];
  int t = threadIdx.x, b = blockIdx.x;
  if (t < NPB) d[t] = 0;
  __syncthreads();
  int s = basep[b], n = tot[b];
  for (int i = t; i < n; i += 256) atomicAdd(&d[binned[s + i] >> 17], 1);
  __syncthreads();
  if (t < NPB) sc[t] = d[t];
  __syncthreads();
  #pragma unroll
  for (int off = 1; off < NPB; off <<= 1) {
    int x = (t < NPB && t >= off) ? sc[t - off] : 0;
    __syncthreads();
    if (t < NPB) sc[t] += x;
    __syncthreads();
  }
  if (t < NPB) {
    int node = b * NPB + t;
    if (node < NN) {
      int dv = d[t];
      deg[node] = dv;
      dinv[node] = rsqrtf((float)(dv + 1));
      rp[node] = s + sc[t] - dv;   // bucket base + exclusive in-bucket prefix
    }
  }
}

// ---------- bucket-local CSR build: one block per bucket; ranks via LDS atomics;
// csr writes confined to the bucket's contiguous edge window.
__global__ void __launch_bounds__(256) k_csr(const unsigned* __restrict__ binned,
                                             const int* __restrict__ basep, const int* __restrict__ tot,
                                             const int* __restrict__ rp, int* __restrict__ csr) {
  __shared__ int srp[NPB];
  __shared__ int cur[NPB];
  int t = threadIdx.x, b = blockIdx.x;
  if (t < NPB) {
    int node = b * NPB + t;
    srp[t] = (node < NN) ? rp[node] : 0;
    cur[t] = 0;
  }
  __syncthreads();
  int s = basep[b], n = tot[b];
  for (int i = t; i < n; i += 256) {
    unsigned u = binned[s + i];
    int src = (int)(u & 0x1FFFFu);
    int dl  = (int)(u >> 17);
    int r = atomicAdd(&cur[dl], 1);
    csr[srp[dl] + r] = src;
  }
}

// ---------- MFMA GEMM: Y = X @ W^T via bf16 hi/lo 3-term split (~fp32 accurate)
template<int K, int MODE>
__global__ void __launch_bounds__(256, 4)
k_gemm(const float* __restrict__ X, const __bf16* __restrict__ Whi, const __bf16* __restrict__ Wlo,
       const float* __restrict__ dinv, const float* __restrict__ bias, void* __restrict__ Yv) {
  constexpr int KT = 32;
  constexpr int NT = K / KT;
  constexpr int LS = 40;
  constexpr int CS = 68;
  __shared__ __align__(16) char smem[4 * 64 * LS * 2];
  __bf16* xh = (__bf16*)smem;
  __bf16* xl = xh + 64 * LS;
  __bf16* wh = xl + 64 * LS;
  __bf16* wl = wh + 64 * LS;
  float*  cl = (float*)smem;

  const int t = threadIdx.x;
  const int l = t & 63;
  const int wc = (t >> 6) * 16;
  const int rowbase = blockIdx.x * 64;

  f32x4 acc[4];
  #pragma unroll
  for (int rt = 0; rt < 4; ++rt) acc[rt] = (f32x4){0.f, 0.f, 0.f, 0.f};

  const int sr = t >> 2;
  const int kc = (t & 3) * 8;

  for (int kt = 0; kt < NT; ++kt) {
    __syncthreads();
    {
      int gr = rowbase + sr;
      float4 v0 = make_float4(0.f, 0.f, 0.f, 0.f), v1 = v0;
      if (gr < NN) {
        const float* xp = X + (size_t)gr * K + kt * KT + kc;
        v0 = *reinterpret_cast<const float4*>(xp);
        v1 = *reinterpret_cast<const float4*>(xp + 4);
      }
      float e[8] = {v0.x, v0.y, v0.z, v0.w, v1.x, v1.y, v1.z, v1.w};
      bf16v8 hv, lv;
      #pragma unroll
      for (int j = 0; j < 8; ++j) {
        __bf16 h = (__bf16)e[j];
        hv[j] = h;
        lv[j] = (__bf16)(e[j] - (float)h);
      }
      *reinterpret_cast<bf16v8*>(&xh[sr * LS + kc]) = hv;
      *reinterpret_cast<bf16v8*>(&xl[sr * LS + kc]) = lv;
      *reinterpret_cast<bf16v8*>(&wh[sr * LS + kc]) =
          *reinterpret_cast<const bf16v8*>(Whi + (size_t)sr * K + kt * KT + kc);
      *reinterpret_cast<bf16v8*>(&wl[sr * LS + kc]) =
          *reinterpret_cast<const bf16v8*>(Wlo + (size_t)sr * K + kt * KT + kc);
    }
    __syncthreads();

    const int bo = (wc + (l & 15)) * LS + (l >> 4) * 8;
    bf16v8 bh = *reinterpret_cast<const bf16v8*>(&wh[bo]);
    bf16v8 bl = *reinterpret_cast<const bf16v8*>(&wl[bo]);
    #pragma unroll
    for (int rt = 0; rt < 4; ++rt) {
      const int ao = (rt * 16 + (l & 15)) * LS + (l >> 4) * 8;
      bf16v8 ah = *reinterpret_cast<const bf16v8*>(&xh[ao]);
      bf16v8 al = *reinterpret_cast<const bf16v8*>(&xl[ao]);
      acc[rt] = __builtin_amdgcn_mfma_f32_16x16x32_bf16(ah, bh, acc[rt], 0, 0, 0);
      acc[rt] = __builtin_amdgcn_mfma_f32_16x16x32_bf16(al, bh, acc[rt], 0, 0, 0);
      acc[rt] = __builtin_amdgcn_mfma_f32_16x16x32_bf16(ah, bl, acc[rt], 0, 0, 0);
    }
  }

  __syncthreads();
  #pragma unroll
  for (int rt = 0; rt < 4; ++rt)
    #pragma unroll
    for (int j = 0; j < 4; ++j)
      cl[(rt * 16 + (l >> 4) * 4 + j) * CS + wc + (l & 15)] = acc[rt][j];
  __syncthreads();

  const int r = t >> 2, cc = (t & 3) * 16;
  const int grow = rowbase + r;
  if (grow < NN) {
    if (MODE == 0) {
      float dv = dinv[grow];
      bf16v8 o0, o1;
      #pragma unroll
      for (int j = 0; j < 8; ++j) o0[j] = (__bf16)(cl[r * CS + cc + j] * dv);
      #pragma unroll
      for (int j = 0; j < 8; ++j) o1[j] = (__bf16)(cl[r * CS + cc + 8 + j] * dv);
      __bf16* yp = (__bf16*)Yv + (size_t)grow * HID + cc;
      *reinterpret_cast<bf16v8*>(yp) = o0;
      *reinterpret_cast<bf16v8*>(yp + 8) = o1;
    } else {
      float* yp = (float*)Yv + (size_t)grow * HID + cc;
      #pragma unroll
      for (int c4 = 0; c4 < 4; ++c4) {
        float4 o;
        o.x = fmaxf(cl[r * CS + cc + c4 * 4 + 0] + bias[cc + c4 * 4 + 0], 0.f);
        o.y = fmaxf(cl[r * CS + cc + c4 * 4 + 1] + bias[cc + c4 * 4 + 1], 0.f);
        o.z = fmaxf(cl[r * CS + cc + c4 * 4 + 2] + bias[cc + c4 * 4 + 2], 0.f);
        o.w = fmaxf(cl[r * CS + cc + c4 * 4 + 3] + bias[cc + c4 * 4 + 3], 0.f);
        *reinterpret_cast<float4*>(yp + c4 * 4) = o;
      }
    }
  }
}

// ---------- aggregation, HALF-WAVE per node: 32 lanes x u32 (2 bf16 features each).
// One gather instruction = 256B covering 2 edges (one per half-wave) -> 2x fewer
// VMEM instructions and 2x bytes-in-flight vs wave-per-node. fp32 accumulate.
// MODE 0 (layer1): O(bf16) = dinv*relu(dinv*sum + bias); MODE 1 (layer2): O(fp32) = dinv*sum.
template<int MODE>
__global__ void __launch_bounds__(256, 8)
k_agg(const unsigned short* __restrict__ T, const int* __restrict__ csr,
      const int* __restrict__ rp, const int* __restrict__ deg,
      const float* __restrict__ dinv, const float* __restrict__ bias,
      void* __restrict__ Ov) {
  const int t = threadIdx.x;
  const int node = blockIdx.x * 8 + (t >> 5);   // 8 half-waves per block
  const int l32 = t & 31;
  const int f = l32 * 2;                        // feature pair

  unsigned su = *reinterpret_cast<const unsigned*>(&T[(size_t)node * HID + f]);
  float acc0 = bf2f((unsigned short)(su & 0xFFFFu));   // self-loop (pre-scaled)
  float acc1 = bf2f((unsigned short)(su >> 16));
  const int start = rp[node];
  const int len = deg[node];

  for (int base = 0; base < len; base += 32) {
    int m = min(32, len - base);
    int idx = (l32 < m) ? csr[start + base + l32] : 0;   // coalesced per half-wave
    for (int c0 = 0; c0 < m; c0 += 16) {
      float p0 = 0.f, p1 = 0.f;
      #pragma unroll
      for (int i = 0; i < 16; ++i) {
        int e = c0 + i;
        int s = __shfl(idx, e & 31, 32);                 // broadcast within half-wave
        unsigned u = *reinterpret_cast<const unsigned*>(&T[(size_t)s * HID + f]);
        if (e < m) {
          p0 += bf2f((unsigned short)(u & 0xFFFFu));
          p1 += bf2f((unsigned short)(u >> 16));
        }
      }
      acc0 += p0;
      acc1 += p1;
    }
  }

  float dv = dinv[node];
  if (MODE == 0) {
    float h0 = dv * fmaxf(fmaf(dv, acc0, bias[f]),     0.f);
    float h1 = dv * fmaxf(fmaf(dv, acc1, bias[f + 1]), 0.f);
    unsigned pack = (unsigned)f2bf(h0) | ((unsigned)f2bf(h1) << 16);
    *reinterpret_cast<unsigned*>((unsigned short*)Ov + (size_t)node * HID + f) = pack;
  } else {
    float2 o;
    o.x = dv * acc0;
    o.y = dv * acc1;
    *reinterpret_cast<float2*>((float*)Ov + (size_t)node * HID + f) = o;
  }
}

extern "C" void kernel_launch(void* const* d_in, const int* in_sizes, int n_in,
                              void* d_out, int out_size, void* d_ws, size_t ws_size,
                              hipStream_t stream) {
  const float* x  = (const float*)d_in[0];
  const int*   ed = (const int*)d_in[1];   // int32 per harness contract
  const float* W1 = (const float*)d_in[2];
  const float* b1 = (const float*)d_in[3];
  const float* W2 = (const float*)d_in[4];
  const float* b2 = (const float*)d_in[5];
  float* out = (float*)d_out;

  char* ws = (char*)d_ws;
  size_t off = 0;
  auto alloc = [&](size_t bytes) {
    char* p = ws + off;
    off = (off + bytes + 255) & ~(size_t)255;
    return p;
  };
  int*      deg    = (int*)alloc((size_t)NN * 4);
  float*    dinv   = (float*)alloc((size_t)NN * 4);
  int*      rp     = (int*)alloc((size_t)NN * 4);
  unsigned* binned = (unsigned*)alloc((size_t)NE * 4);
  int*      csr    = (int*)alloc((size_t)NE * 4);
  int*      bcnt   = (int*)alloc((size_t)NBK * NB * 4);
  int*      tot    = (int*)alloc((size_t)NB * 4);
  int*      basep  = (int*)alloc((size_t)NB * 4);
  // A: first bf16 t1' table (12.8 MB), later fp32 g (25.6 MB)
  float*    A      = (float*)alloc((size_t)NN * HID * 4);
  __bf16*   Whi1   = (__bf16*)alloc((size_t)HID * KIN * 2);
  __bf16*   Wlo1   = (__bf16*)alloc((size_t)HID * KIN * 2);
  __bf16*   Whi2   = (__bf16*)alloc((size_t)HID * HID * 2);
  __bf16*   Wlo2   = (__bf16*)alloc((size_t)HID * HID * 2);
  // h' (bf16, 12.8 MB) lives in d_out's first half; final GEMM overwrites all of d_out.
  unsigned short* Hp = (unsigned short*)d_out;

  // ---- bucket binning -> per-node CSR (all writes bucket-contiguous)
  k_bhist<<<NBK, 256, 0, stream>>>(ed, bcnt);
  k_bscan1<<<(NB + 255) / 256, 256, 0, stream>>>(bcnt, tot);
  k_bscan2<<<1, 1024, 0, stream>>>(tot, basep);
  k_bin<<<NBK, 256, 0, stream>>>(ed, bcnt, basep, binned);
  k_degb2<<<NB, 256, 0, stream>>>(binned, basep, tot, deg, dinv, rp);
  k_csr<<<NB, 256, 0, stream>>>(binned, basep, tot, rp, csr);
  k_wconv2<<<(HID * KIN + HID * HID + 255) / 256, 256, 0, stream>>>(W1, Whi1, Wlo1, W2, Whi2, Wlo2);

  const int GB = (NN + 63) / 64;  // 1563 gemm blocks

  // layer 1: A(bf16) = dinv .* (x @ W1^T) ; Hp(bf16) = dinv .* relu(dinv.*(Agg A) + b1)
  k_gemm<KIN, 0><<<GB, 256, 0, stream>>>(x, Whi1, Wlo1, dinv, b1, A);
  k_agg<0><<<NN / 8, 256, 0, stream>>>((const unsigned short*)A, csr, rp, deg, dinv, b1, Hp);

  // layer 2 (agg commutes with right-linear): A(fp32 g) = dinv .* (Agg Hp) ;
  //          out = relu(g @ W2^T + b2)
  k_agg<1><<<NN / 8, 256, 0, stream>>>(Hp, csr, rp, deg, dinv, b2, A);
  k_gemm<HID, 1><<<GB, 256, 0, stream>>>((const float*)A, Whi2, Wlo2, dinv, b2, out);
}

// Round 16
// 157.285 us; speedup vs baseline: 1.2729x; 1.2729x over previous
//
#include <hip/hip_runtime.h>

static constexpr int NN  = 100000;   // nodes
static constexpr int NE  = 1200000;  // edges
static constexpr int KIN = 256;      // input dim
static constexpr int HID = 64;       // hidden == output dim

static constexpr int BSH   = 7;                        // log2 nodes-per-bucket
static constexpr int NPB   = 1 << BSH;                 // 128 nodes per bucket
static constexpr int NB    = (NN + NPB - 1) / NPB;     // 782 buckets
static constexpr int CAP   = 4096;                     // fixed edge capacity per bucket (exp 1534, 60 sigma)
static constexpr int CHUNK = 8192;                     // edges per binning block
static constexpr int NBK   = (NE + CHUNK - 1) / CHUNK; // 147 binning blocks

typedef __attribute__((ext_vector_type(8))) __bf16 bf16v8;
typedef __attribute__((ext_vector_type(4))) float f32x4;

// ---------- bf16 helpers (exact widen; RNE narrow)
__device__ __forceinline__ float bf2f(unsigned short u) {
  return __uint_as_float(((unsigned int)u) << 16);
}
__device__ __forceinline__ unsigned short f2bf(float f) {
  unsigned int b = __float_as_uint(f);
  return (unsigned short)((b + 0x7FFFu + ((b >> 16) & 1u)) >> 16);
}

// ---------- W tables fp32 -> bf16 hi/lo + zero the bucket cursors (one launch)
__global__ void k_wconv2z(const float* __restrict__ W1, __bf16* __restrict__ Whi1, __bf16* __restrict__ Wlo1,
                          const float* __restrict__ W2, __bf16* __restrict__ Whi2, __bf16* __restrict__ Wlo2,
                          int* __restrict__ gcur) {
  int i = blockIdx.x * 256 + threadIdx.x;
  constexpr int n1 = HID * KIN;
  if (i < n1) {
    float v = W1[i];
    __bf16 h = (__bf16)v;
    Whi1[i] = h;
    Wlo1[i] = (__bf16)(v - (float)h);
  } else if (i < n1 + HID * HID) {
    int j = i - n1;
    float v = W2[j];
    __bf16 h = (__bf16)v;
    Whi2[j] = h;
    Wlo2[j] = (__bf16)(v - (float)h);
  }
  if (i < NB) gcur[i] = 0;
}

// ---------- single-pass binning into fixed-capacity bucket regions.
// Per block: LDS histogram of its chunk -> one global atomicAdd per (block,bucket)
// reserves a contiguous range -> LDS-ranked scatter (writes bucket-contiguous).
__global__ void __launch_bounds__(256) k_bin1p(const int* __restrict__ ed, int* __restrict__ gcur,
                                               unsigned* __restrict__ binned) {
  __shared__ int lcnt[NB];
  __shared__ int lbase[NB];
  int t = threadIdx.x, blk = blockIdx.x;
  for (int i = t; i < NB; i += 256) lcnt[i] = 0;
  __syncthreads();
  int base = blk * CHUNK;
  #pragma unroll
  for (int it = 0; it < CHUNK / 256; ++it) {          // pass 1: count
    int e = base + it * 256 + t;
    if (e < NE) atomicAdd(&lcnt[ed[NE + e] >> BSH], 1);
  }
  __syncthreads();
  for (int i = t; i < NB; i += 256) {                  // reserve ranges
    int c = lcnt[i];
    lbase[i] = (c > 0) ? atomicAdd(&gcur[i], c) : 0;
    lcnt[i] = 0;                                       // reuse as rank counter
  }
  __syncthreads();
  #pragma unroll
  for (int it = 0; it < CHUNK / 256; ++it) {          // pass 2: scatter (ed chunk L2-hot)
    int e = base + it * 256 + t;
    if (e < NE) {
      int src = ed[e];
      int dst = ed[NE + e];
      int b = dst >> BSH;
      int r = atomicAdd(&lcnt[b], 1);
      binned[(size_t)b * CAP + lbase[b] + r] = (unsigned)src | ((unsigned)(dst & (NPB - 1)) << 17);
    }
  }
}

// ---------- fused per-bucket: degree + dinv + rp + CSR scatter (window stays L2-hot).
// rp[node] = b*CAP + exclusive in-bucket prefix; csr shares the fixed-capacity layout.
__global__ void __launch_bounds__(256) k_degcsr(const unsigned* __restrict__ binned,
                                                const int* __restrict__ gcur,
                                                int* __restrict__ deg, float* __restrict__ dinv,
                                                int* __restrict__ rp, int* __restrict__ csr) {
  __shared__ int d[NPB];
  __shared__ int sc[NPB];
  __shared__ int cur[NPB];
  int t = threadIdx.x, b = blockIdx.x;
  if (t < NPB) { d[t] = 0; cur[t] = 0; }
  __syncthreads();
  const int n = gcur[b];
  const unsigned* win = binned + (size_t)b * CAP;
  for (int i = t; i < n; i += 256) atomicAdd(&d[win[i] >> 17], 1);
  __syncthreads();
  if (t < NPB) sc[t] = d[t];
  __syncthreads();
  #pragma unroll
  for (int off = 1; off < NPB; off <<= 1) {
    int x = (t < NPB && t >= off) ? sc[t - off] : 0;
    __syncthreads();
    if (t < NPB) sc[t] += x;
    __syncthreads();
  }
  if (t < NPB) {
    int node = b * NPB + t;
    if (node < NN) {
      deg[node] = d[t];
      dinv[node] = rsqrtf((float)(d[t] + 1));
      rp[node] = b * CAP + sc[t] - d[t];
    }
  }
  __syncthreads();
  for (int i = t; i < n; i += 256) {                   // csr scatter (win L2-hot)
    unsigned u = win[i];
    int src = (int)(u & 0x1FFFFu);
    int dl  = (int)(u >> 17);
    int r = atomicAdd(&cur[dl], 1);
    csr[(size_t)b * CAP + (sc[dl] - d[dl]) + r] = src;
  }
}

// ---------- MFMA GEMM: Y = X @ W^T via bf16 hi/lo 3-term split (~fp32 accurate)
template<int K, int MODE>
__global__ void __launch_bounds__(256, 4)
k_gemm(const float* __restrict__ X, const __bf16* __restrict__ Whi, const __bf16* __restrict__ Wlo,
       const float* __restrict__ dinv, const float* __restrict__ bias, void* __restrict__ Yv) {
  constexpr int KT = 32;
  constexpr int NT = K / KT;
  constexpr int LS = 40;
  constexpr int CS = 68;
  __shared__ __align__(16) char smem[4 * 64 * LS * 2];
  __bf16* xh = (__bf16*)smem;
  __bf16* xl = xh + 64 * LS;
  __bf16* wh = xl + 64 * LS;
  __bf16* wl = wh + 64 * LS;
  float*  cl = (float*)smem;

  const int t = threadIdx.x;
  const int l = t & 63;
  const int wc = (t >> 6) * 16;
  const int rowbase = blockIdx.x * 64;

  f32x4 acc[4];
  #pragma unroll
  for (int rt = 0; rt < 4; ++rt) acc[rt] = (f32x4){0.f, 0.f, 0.f, 0.f};

  const int sr = t >> 2;
  const int kc = (t & 3) * 8;

  for (int kt = 0; kt < NT; ++kt) {
    __syncthreads();
    {
      int gr = rowbase + sr;
      float4 v0 = make_float4(0.f, 0.f, 0.f, 0.f), v1 = v0;
      if (gr < NN) {
        const float* xp = X + (size_t)gr * K + kt * KT + kc;
        v0 = *reinterpret_cast<const float4*>(xp);
        v1 = *reinterpret_cast<const float4*>(xp + 4);
      }
      float e[8] = {v0.x, v0.y, v0.z, v0.w, v1.x, v1.y, v1.z, v1.w};
      bf16v8 hv, lv;
      #pragma unroll
      for (int j = 0; j < 8; ++j) {
        __bf16 h = (__bf16)e[j];
        hv[j] = h;
        lv[j] = (__bf16)(e[j] - (float)h);
      }
      *reinterpret_cast<bf16v8*>(&xh[sr * LS + kc]) = hv;
      *reinterpret_cast<bf16v8*>(&xl[sr * LS + kc]) = lv;
      *reinterpret_cast<bf16v8*>(&wh[sr * LS + kc]) =
          *reinterpret_cast<const bf16v8*>(Whi + (size_t)sr * K + kt * KT + kc);
      *reinterpret_cast<bf16v8*>(&wl[sr * LS + kc]) =
          *reinterpret_cast<const bf16v8*>(Wlo + (size_t)sr * K + kt * KT + kc);
    }
    __syncthreads();

    const int bo = (wc + (l & 15)) * LS + (l >> 4) * 8;
    bf16v8 bh = *reinterpret_cast<const bf16v8*>(&wh[bo]);
    bf16v8 bl = *reinterpret_cast<const bf16v8*>(&wl[bo]);
    #pragma unroll
    for (int rt = 0; rt < 4; ++rt) {
      const int ao = (rt * 16 + (l & 15)) * LS + (l >> 4) * 8;
      bf16v8 ah = *reinterpret_cast<const bf16v8*>(&xh[ao]);
      bf16v8 al = *reinterpret_cast<const bf16v8*>(&xl[ao]);
      acc[rt] = __builtin_amdgcn_mfma_f32_16x16x32_bf16(ah, bh, acc[rt], 0, 0, 0);
      acc[rt] = __builtin_amdgcn_mfma_f32_16x16x32_bf16(al, bh, acc[rt], 0, 0, 0);
      acc[rt] = __builtin_amdgcn_mfma_f32_16x16x32_bf16(ah, bl, acc[rt], 0, 0, 0);
    }
  }

  __syncthreads();
  #pragma unroll
  for (int rt = 0; rt < 4; ++rt)
    #pragma unroll
    for (int j = 0; j < 4; ++j)
      cl[(rt * 16 + (l >> 4) * 4 + j) * CS + wc + (l & 15)] = acc[rt][j];
  __syncthreads();

  const int r = t >> 2, cc = (t & 3) * 16;
  const int grow = rowbase + r;
  if (grow < NN) {
    if (MODE == 0) {
      float dv = dinv[grow];
      bf16v8 o0, o1;
      #pragma unroll
      for (int j = 0; j < 8; ++j) o0[j] = (__bf16)(cl[r * CS + cc + j] * dv);
      #pragma unroll
      for (int j = 0; j < 8; ++j) o1[j] = (__bf16)(cl[r * CS + cc + 8 + j] * dv);
      __bf16* yp = (__bf16*)Yv + (size_t)grow * HID + cc;
      *reinterpret_cast<bf16v8*>(yp) = o0;
      *reinterpret_cast<bf16v8*>(yp + 8) = o1;
    } else {
      float* yp = (float*)Yv + (size_t)grow * HID + cc;
      #pragma unroll
      for (int c4 = 0; c4 < 4; ++c4) {
        float4 o;
        o.x = fmaxf(cl[r * CS + cc + c4 * 4 + 0] + bias[cc + c4 * 4 + 0], 0.f);
        o.y = fmaxf(cl[r * CS + cc + c4 * 4 + 1] + bias[cc + c4 * 4 + 1], 0.f);
        o.z = fmaxf(cl[r * CS + cc + c4 * 4 + 2] + bias[cc + c4 * 4 + 2], 0.f);
        o.w = fmaxf(cl[r * CS + cc + c4 * 4 + 3] + bias[cc + c4 * 4 + 3], 0.f);
        *reinterpret_cast<float4*>(yp + c4 * 4) = o;
      }
    }
  }
}

// ---------- aggregation (round-14 form: wave per node, lane = feature, bf16 gathers,
// 16 loads in flight). fp32 accumulate.
// MODE 0 (layer1): O(bf16) = dinv*relu(dinv*sum + bias); MODE 1 (layer2): O(fp32) = dinv*sum.
template<int MODE>
__global__ void __launch_bounds__(256, 8)
k_agg(const unsigned short* __restrict__ T, const int* __restrict__ csr,
      const int* __restrict__ rp, const int* __restrict__ deg,
      const float* __restrict__ dinv, const float* __restrict__ bias,
      void* __restrict__ Ov) {
  int node = blockIdx.x * 4 + (threadIdx.x >> 6);
  int lane = threadIdx.x & 63;
  float acc = bf2f(T[(size_t)node * HID + lane]);   // self-loop term (pre-scaled)
  int start = rp[node];
  int len = deg[node];
  for (int base = 0; base < len; base += 64) {
    int m = min(64, len - base);
    int idx = (lane < m) ? csr[start + base + lane] : 0;   // coalesced index load
    for (int c0 = 0; c0 < m; c0 += 16) {
      float part = 0.f;
      #pragma unroll
      for (int i = 0; i < 16; ++i) {
        int e = c0 + i;
        int s = __shfl(idx, e & 63);
        float v = bf2f(T[(size_t)s * HID + lane]);   // always issued; 16 in flight
        part += (e < m) ? v : 0.f;
      }
      acc += part;
    }
  }
  float dv = dinv[node];
  if (MODE == 0) {
    float h = dv * fmaxf(fmaf(dv, acc, bias[lane]), 0.f);
    ((unsigned short*)Ov)[(size_t)node * HID + lane] = f2bf(h);
  } else {
    ((float*)Ov)[(size_t)node * HID + lane] = dv * acc;
  }
}

extern "C" void kernel_launch(void* const* d_in, const int* in_sizes, int n_in,
                              void* d_out, int out_size, void* d_ws, size_t ws_size,
                              hipStream_t stream) {
  const float* x  = (const float*)d_in[0];
  const int*   ed = (const int*)d_in[1];   // int32 per harness contract
  const float* W1 = (const float*)d_in[2];
  const float* b1 = (const float*)d_in[3];
  const float* W2 = (const float*)d_in[4];
  const float* b2 = (const float*)d_in[5];
  float* out = (float*)d_out;

  char* ws = (char*)d_ws;
  size_t off = 0;
  auto alloc = [&](size_t bytes) {
    char* p = ws + off;
    off = (off + bytes + 255) & ~(size_t)255;
    return p;
  };
  int*      deg    = (int*)alloc((size_t)NN * 4);
  float*    dinv   = (float*)alloc((size_t)NN * 4);
  int*      rp     = (int*)alloc((size_t)NN * 4);
  int*      gcur   = (int*)alloc((size_t)NB * 4);
  unsigned* binned = (unsigned*)alloc((size_t)NB * CAP * 4);   // 12.8 MB
  int*      csr    = (int*)alloc((size_t)NB * CAP * 4);        // 12.8 MB
  // A: first bf16 t1' table (12.8 MB), later fp32 g (25.6 MB)
  float*    A      = (float*)alloc((size_t)NN * HID * 4);
  __bf16*   Whi1   = (__bf16*)alloc((size_t)HID * KIN * 2);
  __bf16*   Wlo1   = (__bf16*)alloc((size_t)HID * KIN * 2);
  __bf16*   Whi2   = (__bf16*)alloc((size_t)HID * HID * 2);
  __bf16*   Wlo2   = (__bf16*)alloc((size_t)HID * HID * 2);
  // h' (bf16, 12.8 MB) lives in d_out's first half; final GEMM overwrites all of d_out.
  unsigned short* Hp = (unsigned short*)d_out;

  // ---- preprocessing: 3 launches
  k_wconv2z<<<(HID * KIN + HID * HID + 255) / 256, 256, 0, stream>>>(W1, Whi1, Wlo1, W2, Whi2, Wlo2, gcur);
  k_bin1p<<<NBK, 256, 0, stream>>>(ed, gcur, binned);
  k_degcsr<<<NB, 256, 0, stream>>>(binned, gcur, deg, dinv, rp, csr);

  const int GB = (NN + 63) / 64;  // 1563 gemm blocks

  // layer 1: A(bf16) = dinv .* (x @ W1^T) ; Hp(bf16) = dinv .* relu(dinv.*(Agg A) + b1)
  k_gemm<KIN, 0><<<GB, 256, 0, stream>>>(x, Whi1, Wlo1, dinv, b1, A);
  k_agg<0><<<NN / 4, 256, 0, stream>>>((const unsigned short*)A, csr, rp, deg, dinv, b1, Hp);

  // layer 2 (agg commutes with right-linear): A(fp32 g) = dinv .* (Agg Hp) ;
  //          out = relu(g @ W2^T + b2)
  k_agg<1><<<NN / 4, 256, 0, stream>>>(Hp, csr, rp, deg, dinv, b2, A);
  k_gemm<HID, 1><<<GB, 256, 0, stream>>>((const float*)A, Whi2, Wlo2, dinv, b2, out);
}

// Round 17
// 154.261 us; speedup vs baseline: 1.2979x; 1.0196x over previous
//
#include <hip/hip_runtime.h>

static constexpr int NN  = 100000;   // nodes
static constexpr int NE  = 1200000;  // edges
static constexpr int KIN = 256;      // input dim
static constexpr int HID = 64;       // hidden == output dim

static constexpr int BSH   = 7;                        // log2 nodes-per-bucket
static constexpr int NPB   = 1 << BSH;                 // 128 nodes per bucket
static constexpr int NB    = (NN + NPB - 1) / NPB;     // 782 buckets
static constexpr int CAP   = 4096;                     // fixed edge capacity per bucket
static constexpr int CHUNK = 8192;                     // edges per binning block
static constexpr int NBK   = (NE + CHUNK - 1) / CHUNK; // 147 binning blocks

typedef __attribute__((ext_vector_type(8))) __bf16 bf16v8;
typedef __attribute__((ext_vector_type(4))) float f32x4;

// ---------- bf16 helpers (exact widen; RNE narrow)
__device__ __forceinline__ float bf2f(unsigned short u) {
  return __uint_as_float(((unsigned int)u) << 16);
}
__device__ __forceinline__ unsigned short f2bf(float f) {
  unsigned int b = __float_as_uint(f);
  return (unsigned short)((b + 0x7FFFu + ((b >> 16) & 1u)) >> 16);
}

// ---------- W tables fp32 -> bf16 hi/lo + zero the bucket cursors (one launch)
__global__ void k_wconv2z(const float* __restrict__ W1, __bf16* __restrict__ Whi1, __bf16* __restrict__ Wlo1,
                          const float* __restrict__ W2, __bf16* __restrict__ Whi2, __bf16* __restrict__ Wlo2,
                          int* __restrict__ gcur) {
  int i = blockIdx.x * 256 + threadIdx.x;
  constexpr int n1 = HID * KIN;
  if (i < n1) {
    float v = W1[i];
    __bf16 h = (__bf16)v;
    Whi1[i] = h;
    Wlo1[i] = (__bf16)(v - (float)h);
  } else if (i < n1 + HID * HID) {
    int j = i - n1;
    float v = W2[j];
    __bf16 h = (__bf16)v;
    Whi2[j] = h;
    Wlo2[j] = (__bf16)(v - (float)h);
  }
  if (i < NB) gcur[i] = 0;
}

// ---------- single-pass binning into fixed-capacity bucket regions.
__global__ void __launch_bounds__(256) k_bin1p(const int* __restrict__ ed, int* __restrict__ gcur,
                                               unsigned* __restrict__ binned) {
  __shared__ int lcnt[NB];
  __shared__ int lbase[NB];
  int t = threadIdx.x, blk = blockIdx.x;
  for (int i = t; i < NB; i += 256) lcnt[i] = 0;
  __syncthreads();
  int base = blk * CHUNK;
  #pragma unroll
  for (int it = 0; it < CHUNK / 256; ++it) {          // pass 1: count
    int e = base + it * 256 + t;
    if (e < NE) atomicAdd(&lcnt[ed[NE + e] >> BSH], 1);
  }
  __syncthreads();
  for (int i = t; i < NB; i += 256) {                  // reserve ranges
    int c = lcnt[i];
    lbase[i] = (c > 0) ? atomicAdd(&gcur[i], c) : 0;
    lcnt[i] = 0;                                       // reuse as rank counter
  }
  __syncthreads();
  #pragma unroll
  for (int it = 0; it < CHUNK / 256; ++it) {          // pass 2: scatter (ed chunk L2-hot)
    int e = base + it * 256 + t;
    if (e < NE) {
      int src = ed[e];
      int dst = ed[NE + e];
      int b = dst >> BSH;
      int r = atomicAdd(&lcnt[b], 1);
      binned[(size_t)b * CAP + lbase[b] + r] = (unsigned)src | ((unsigned)(dst & (NPB - 1)) << 17);
    }
  }
}

// ---------- fused per-bucket: degree + dinv + rp + CSR scatter (window L2-hot)
__global__ void __launch_bounds__(256) k_degcsr(const unsigned* __restrict__ binned,
                                                const int* __restrict__ gcur,
                                                int* __restrict__ deg, float* __restrict__ dinv,
                                                int* __restrict__ rp, int* __restrict__ csr) {
  __shared__ int d[NPB];
  __shared__ int sc[NPB];
  __shared__ int cur[NPB];
  int t = threadIdx.x, b = blockIdx.x;
  if (t < NPB) { d[t] = 0; cur[t] = 0; }
  __syncthreads();
  const int n = gcur[b];
  const unsigned* win = binned + (size_t)b * CAP;
  for (int i = t; i < n; i += 256) atomicAdd(&d[win[i] >> 17], 1);
  __syncthreads();
  if (t < NPB) sc[t] = d[t];
  __syncthreads();
  #pragma unroll
  for (int off = 1; off < NPB; off <<= 1) {
    int x = (t < NPB && t >= off) ? sc[t - off] : 0;
    __syncthreads();
    if (t < NPB) sc[t] += x;
    __syncthreads();
  }
  if (t < NPB) {
    int node = b * NPB + t;
    if (node < NN) {
      deg[node] = d[t];
      dinv[node] = rsqrtf((float)(d[t] + 1));
      rp[node] = b * CAP + sc[t] - d[t];
    }
  }
  __syncthreads();
  for (int i = t; i < n; i += 256) {
    unsigned u = win[i];
    int src = (int)(u & 0x1FFFFu);
    int dl  = (int)(u >> 17);
    int r = atomicAdd(&cur[dl], 1);
    csr[(size_t)b * CAP + (sc[dl] - d[dl]) + r] = src;
  }
}

// ---------- MFMA GEMM: Y = X @ W^T via bf16 hi/lo 3-term split (~fp32 accurate)
// MODE 0: Y(bf16) = dinv[r]*acc; MODE 1: Y(fp32) = relu(acc + bias).
template<int K, int MODE>
__global__ void __launch_bounds__(256, 4)
k_gemm(const float* __restrict__ X, const __bf16* __restrict__ Whi, const __bf16* __restrict__ Wlo,
       const float* __restrict__ dinv, const float* __restrict__ bias, void* __restrict__ Yv) {
  constexpr int KT = 32;
  constexpr int NT = K / KT;
  constexpr int LS = 40;
  constexpr int CS = 68;
  __shared__ __align__(16) char smem[4 * 64 * LS * 2];
  __bf16* xh = (__bf16*)smem;
  __bf16* xl = xh + 64 * LS;
  __bf16* wh = xl + 64 * LS;
  __bf16* wl = wh + 64 * LS;
  float*  cl = (float*)smem;

  const int t = threadIdx.x;
  const int l = t & 63;
  const int wc = (t >> 6) * 16;
  const int rowbase = blockIdx.x * 64;

  f32x4 acc[4];
  #pragma unroll
  for (int rt = 0; rt < 4; ++rt) acc[rt] = (f32x4){0.f, 0.f, 0.f, 0.f};

  const int sr = t >> 2;
  const int kc = (t & 3) * 8;

  for (int kt = 0; kt < NT; ++kt) {
    __syncthreads();
    {
      int gr = rowbase + sr;
      float4 v0 = make_float4(0.f, 0.f, 0.f, 0.f), v1 = v0;
      if (gr < NN) {
        const float* xp = X + (size_t)gr * K + kt * KT + kc;
        v0 = *reinterpret_cast<const float4*>(xp);
        v1 = *reinterpret_cast<const float4*>(xp + 4);
      }
      float e[8] = {v0.x, v0.y, v0.z, v0.w, v1.x, v1.y, v1.z, v1.w};
      bf16v8 hv, lv;
      #pragma unroll
      for (int j = 0; j < 8; ++j) {
        __bf16 h = (__bf16)e[j];
        hv[j] = h;
        lv[j] = (__bf16)(e[j] - (float)h);
      }
      *reinterpret_cast<bf16v8*>(&xh[sr * LS + kc]) = hv;
      *reinterpret_cast<bf16v8*>(&xl[sr * LS + kc]) = lv;
      *reinterpret_cast<bf16v8*>(&wh[sr * LS + kc]) =
          *reinterpret_cast<const bf16v8*>(Whi + (size_t)sr * K + kt * KT + kc);
      *reinterpret_cast<bf16v8*>(&wl[sr * LS + kc]) =
          *reinterpret_cast<const bf16v8*>(Wlo + (size_t)sr * K + kt * KT + kc);
    }
    __syncthreads();

    const int bo = (wc + (l & 15)) * LS + (l >> 4) * 8;
    bf16v8 bh = *reinterpret_cast<const bf16v8*>(&wh[bo]);
    bf16v8 bl = *reinterpret_cast<const bf16v8*>(&wl[bo]);
    #pragma unroll
    for (int rt = 0; rt < 4; ++rt) {
      const int ao = (rt * 16 + (l & 15)) * LS + (l >> 4) * 8;
      bf16v8 ah = *reinterpret_cast<const bf16v8*>(&xh[ao]);
      bf16v8 al = *reinterpret_cast<const bf16v8*>(&xl[ao]);
      acc[rt] = __builtin_amdgcn_mfma_f32_16x16x32_bf16(ah, bh, acc[rt], 0, 0, 0);
      acc[rt] = __builtin_amdgcn_mfma_f32_16x16x32_bf16(al, bh, acc[rt], 0, 0, 0);
      acc[rt] = __builtin_amdgcn_mfma_f32_16x16x32_bf16(ah, bl, acc[rt], 0, 0, 0);
    }
  }

  __syncthreads();
  #pragma unroll
  for (int rt = 0; rt < 4; ++rt)
    #pragma unroll
    for (int j = 0; j < 4; ++j)
      cl[(rt * 16 + (l >> 4) * 4 + j) * CS + wc + (l & 15)] = acc[rt][j];
  __syncthreads();

  const int r = t >> 2, cc = (t & 3) * 16;
  const int grow = rowbase + r;
  if (grow < NN) {
    if (MODE == 0) {
      float dv = dinv[grow];
      bf16v8 o0, o1;
      #pragma unroll
      for (int j = 0; j < 8; ++j) o0[j] = (__bf16)(cl[r * CS + cc + j] * dv);
      #pragma unroll
      for (int j = 0; j < 8; ++j) o1[j] = (__bf16)(cl[r * CS + cc + 8 + j] * dv);
      __bf16* yp = (__bf16*)Yv + (size_t)grow * HID + cc;
      *reinterpret_cast<bf16v8*>(yp) = o0;
      *reinterpret_cast<bf16v8*>(yp + 8) = o1;
    } else {
      float* yp = (float*)Yv + (size_t)grow * HID + cc;
      #pragma unroll
      for (int c4 = 0; c4 < 4; ++c4) {
        float4 o;
        o.x = fmaxf(cl[r * CS + cc + c4 * 4 + 0] + bias[cc + c4 * 4 + 0], 0.f);
        o.y = fmaxf(cl[r * CS + cc + c4 * 4 + 1] + bias[cc + c4 * 4 + 1], 0.f);
        o.z = fmaxf(cl[r * CS + cc + c4 * 4 + 2] + bias[cc + c4 * 4 + 2], 0.f);
        o.w = fmaxf(cl[r * CS + cc + c4 * 4 + 3] + bias[cc + c4 * 4 + 3], 0.f);
        *reinterpret_cast<float4*>(yp + c4 * 4) = o;
      }
    }
  }
}

// ---------- standalone agg (layer 1): wave per node, lane = feature, bf16 gathers.
// O(bf16) = dinv*relu(dinv*sum + bias)
__global__ void __launch_bounds__(256, 8)
k_agg(const unsigned short* __restrict__ T, const int* __restrict__ csr,
      const int* __restrict__ rp, const int* __restrict__ deg,
      const float* __restrict__ dinv, const float* __restrict__ bias,
      unsigned short* __restrict__ Ov) {
  int node = blockIdx.x * 4 + (threadIdx.x >> 6);
  int lane = threadIdx.x & 63;
  float acc = bf2f(T[(size_t)node * HID + lane]);   // self-loop term (pre-scaled)
  int start = rp[node];
  int len = deg[node];
  for (int base = 0; base < len; base += 64) {
    int m = min(64, len - base);
    int idx = (lane < m) ? csr[start + base + lane] : 0;
    for (int c0 = 0; c0 < m; c0 += 16) {
      float part = 0.f;
      #pragma unroll
      for (int i = 0; i < 16; ++i) {
        int e = c0 + i;
        int s = __shfl(idx, e & 63);
        float v = bf2f(T[(size_t)s * HID + lane]);   // 16 in flight
        part += (e < m) ? v : 0.f;
      }
      acc += part;
    }
  }
  float dv = dinv[node];
  float h = dv * fmaxf(fmaf(dv, acc, bias[lane]), 0.f);
  Ov[(size_t)node * HID + lane] = f2bf(h);
}

// ---------- FUSED agg(layer2) + GEMM2: block = 64 nodes.
// Phase A: wave w computes g rows [w*16, w*16+16) (wave-per-node, serial 16), writes
//          bf16 hi/lo to LDS.  g = dinv .* (Agg Hp)
// Phase B: out = relu(g @ W2^T + b2); W2 hi/lo frags read from global (8 KB, L1-hot).
__global__ void __launch_bounds__(256, 8)
k_aggemm(const unsigned short* __restrict__ T, const int* __restrict__ csr,
         const int* __restrict__ rp, const int* __restrict__ deg,
         const float* __restrict__ dinv,
         const __bf16* __restrict__ Whi2, const __bf16* __restrict__ Wlo2,
         const float* __restrict__ bias, float* __restrict__ out) {
  constexpr int LS = 72;                 // bf16 row stride for g tiles
  constexpr int CS = 68;                 // epilogue f32 row stride
  __shared__ __align__(16) char smem[2 * 64 * LS * 2];   // 18432 B
  __bf16* gh = (__bf16*)smem;
  __bf16* gl = gh + 64 * LS;
  float*  cl = (float*)smem;             // epilogue overlay (17408 B)

  const int t = threadIdx.x;
  const int l = t & 63;
  const int w = t >> 6;
  const int rowbase = blockIdx.x * 64;

  // ---- phase A: aggregate 16 nodes per wave
  for (int i = 0; i < 16; ++i) {
    int node = rowbase + w * 16 + i;
    float gv = 0.f;
    if (node < NN) {
      float acc = bf2f(T[(size_t)node * HID + l]);   // self-loop
      int start = rp[node];
      int len = deg[node];
      for (int base = 0; base < len; base += 64) {
        int m = min(64, len - base);
        int idx = (l < m) ? csr[start + base + l] : 0;
        for (int c0 = 0; c0 < m; c0 += 16) {
          float part = 0.f;
          #pragma unroll
          for (int j = 0; j < 16; ++j) {
            int e = c0 + j;
            int s = __shfl(idx, e & 63);
            float v = bf2f(T[(size_t)s * HID + l]);
            part += (e < m) ? v : 0.f;
          }
          acc += part;
        }
      }
      gv = dinv[node] * acc;
    }
    __bf16 h = (__bf16)gv;
    int r = w * 16 + i;
    gh[r * LS + l] = h;
    gl[r * LS + l] = (__bf16)(gv - (float)h);
  }
  __syncthreads();

  // ---- phase B: MFMA, wave = 16-col slab
  const int wc = w * 16;
  f32x4 acc[4];
  #pragma unroll
  for (int rt = 0; rt < 4; ++rt) acc[rt] = (f32x4){0.f, 0.f, 0.f, 0.f};
  #pragma unroll
  for (int kc = 0; kc < 2; ++kc) {
    const size_t wo = (size_t)(wc + (l & 15)) * HID + kc * 32 + (l >> 4) * 8;
    bf16v8 bh = *reinterpret_cast<const bf16v8*>(Whi2 + wo);
    bf16v8 bl = *reinterpret_cast<const bf16v8*>(Wlo2 + wo);
    #pragma unroll
    for (int rt = 0; rt < 4; ++rt) {
      const int ao = (rt * 16 + (l & 15)) * LS + kc * 32 + (l >> 4) * 8;
      bf16v8 ah = *reinterpret_cast<const bf16v8*>(&gh[ao]);
      bf16v8 al = *reinterpret_cast<const bf16v8*>(&gl[ao]);
      acc[rt] = __builtin_amdgcn_mfma_f32_16x16x32_bf16(ah, bh, acc[rt], 0, 0, 0);
      acc[rt] = __builtin_amdgcn_mfma_f32_16x16x32_bf16(al, bh, acc[rt], 0, 0, 0);
      acc[rt] = __builtin_amdgcn_mfma_f32_16x16x32_bf16(ah, bl, acc[rt], 0, 0, 0);
    }
  }
  __syncthreads();                       // gh/gl dead; overlay cl
  #pragma unroll
  for (int rt = 0; rt < 4; ++rt)
    #pragma unroll
    for (int j = 0; j < 4; ++j)
      cl[(rt * 16 + (l >> 4) * 4 + j) * CS + wc + (l & 15)] = acc[rt][j];
  __syncthreads();

  const int r = t >> 2, cc = (t & 3) * 16;
  const int grow = rowbase + r;
  if (grow < NN) {
    float* yp = out + (size_t)grow * HID + cc;
    #pragma unroll
    for (int c4 = 0; c4 < 4; ++c4) {
      float4 o;
      o.x = fmaxf(cl[r * CS + cc + c4 * 4 + 0] + bias[cc + c4 * 4 + 0], 0.f);
      o.y = fmaxf(cl[r * CS + cc + c4 * 4 + 1] + bias[cc + c4 * 4 + 1], 0.f);
      o.z = fmaxf(cl[r * CS + cc + c4 * 4 + 2] + bias[cc + c4 * 4 + 2], 0.f);
      o.w = fmaxf(cl[r * CS + cc + c4 * 4 + 3] + bias[cc + c4 * 4 + 3], 0.f);
      *reinterpret_cast<float4*>(yp + c4 * 4) = o;
    }
  }
}

extern "C" void kernel_launch(void* const* d_in, const int* in_sizes, int n_in,
                              void* d_out, int out_size, void* d_ws, size_t ws_size,
                              hipStream_t stream) {
  const float* x  = (const float*)d_in[0];
  const int*   ed = (const int*)d_in[1];   // int32 per harness contract
  const float* W1 = (const float*)d_in[2];
  const float* b1 = (const float*)d_in[3];
  const float* W2 = (const float*)d_in[4];
  const float* b2 = (const float*)d_in[5];
  float* out = (float*)d_out;

  char* ws = (char*)d_ws;
  size_t off = 0;
  auto alloc = [&](size_t bytes) {
    char* p = ws + off;
    off = (off + bytes + 255) & ~(size_t)255;
    return p;
  };
  int*      deg    = (int*)alloc((size_t)NN * 4);
  float*    dinv   = (float*)alloc((size_t)NN * 4);
  int*      rp     = (int*)alloc((size_t)NN * 4);
  int*      gcur   = (int*)alloc((size_t)NB * 4);
  unsigned* binned = (unsigned*)alloc((size_t)NB * CAP * 4);     // 12.8 MB
  int*      csr    = (int*)alloc((size_t)NB * CAP * 4);          // 12.8 MB
  unsigned short* T1 = (unsigned short*)alloc((size_t)NN * HID * 2);  // 12.8 MB bf16 t1'
  unsigned short* Hp = (unsigned short*)alloc((size_t)NN * HID * 2);  // 12.8 MB bf16 h'
  __bf16*   Whi1   = (__bf16*)alloc((size_t)HID * KIN * 2);
  __bf16*   Wlo1   = (__bf16*)alloc((size_t)HID * KIN * 2);
  __bf16*   Whi2   = (__bf16*)alloc((size_t)HID * HID * 2);
  __bf16*   Wlo2   = (__bf16*)alloc((size_t)HID * HID * 2);

  // ---- preprocessing: 3 launches
  k_wconv2z<<<(HID * KIN + HID * HID + 255) / 256, 256, 0, stream>>>(W1, Whi1, Wlo1, W2, Whi2, Wlo2, gcur);
  k_bin1p<<<NBK, 256, 0, stream>>>(ed, gcur, binned);
  k_degcsr<<<NB, 256, 0, stream>>>(binned, gcur, deg, dinv, rp, csr);

  const int GB = (NN + 63) / 64;  // 1563 blocks

  // layer 1: T1(bf16) = dinv .* (x @ W1^T) ; Hp(bf16) = dinv .* relu(dinv.*(Agg T1) + b1)
  k_gemm<KIN, 0><<<GB, 256, 0, stream>>>(x, Whi1, Wlo1, dinv, b1, (void*)T1);
  k_agg<<<NN / 4, 256, 0, stream>>>(T1, csr, rp, deg, dinv, b1, Hp);

  // layer 2 fused: out = relu((dinv .* Agg Hp) @ W2^T + b2)
  k_aggemm<<<GB, 256, 0, stream>>>(Hp, csr, rp, deg, dinv, Whi2, Wlo2, b2, out);
}